// Round 1
// 895.489 us; speedup vs baseline: 1.3293x; 1.3293x over previous
//
#include <hip/hip_runtime.h>

#define NT 8192
#define DM 2048
#define DH 2048
#define NE 16

typedef __attribute__((ext_vector_type(8))) short short8;
typedef __attribute__((ext_vector_type(4))) float floatx4;

__device__ __forceinline__ unsigned short f2bf(float f){
  union { float f; unsigned u; } c; c.f = f;
  unsigned r = 0x7FFFu + ((c.u >> 16) & 1u);
  return (unsigned short)((c.u + r) >> 16);
}
// pack two floats as adjacent bf16 (lo in low 16 bits)
__device__ __forceinline__ unsigned pk(float lo, float hi){
  return ((unsigned)f2bf(hi) << 16) | (unsigned)f2bf(lo);
}

// async global -> LDS, 16B per lane; LDS dest is wave-uniform base + lane*16
__device__ __forceinline__ void gload_lds16(const void* g, void* l){
  __builtin_amdgcn_global_load_lds(
      (__attribute__((address_space(1))) void*)(unsigned long long)g,
      (__attribute__((address_space(3))) void*)l, 16, 0, 0);
}

// ---------------- f32 -> bf16 bulk convert (x) ----------------
__global__ __launch_bounds__(256) void cvt_kernel(
    const float4* __restrict__ src, uint2* __restrict__ dst, int n4)
{
  int i = blockIdx.x * 256 + threadIdx.x;
  if (i < n4){
    float4 v = src[i];
    dst[i] = make_uint2(pk(v.x, v.y), pk(v.z, v.w));
  }
}

// ------- f32 [e][d][h] -> bf16 [e][h][d] transpose+convert, 64x64 tiles -------
__global__ __launch_bounds__(256) void cvt_wt_kernel(
    const float* __restrict__ w, unsigned short* __restrict__ wt)
{
  __shared__ unsigned short t[64][72];   // pad 72 -> 16B-aligned row chunks
  const int e = blockIdx.z;
  const int h0 = blockIdx.x * 64, d0 = blockIdx.y * 64;
  const size_t ib = (size_t)e * DM * DH;
  const int r = threadIdx.x >> 2;          // 0..63
  const int c = (threadIdx.x & 3) * 16;    // 0,16,32,48
  const float4* src = (const float4*)(w + ib + (size_t)(d0 + r) * DH + h0 + c);
  #pragma unroll
  for (int i = 0; i < 4; i++){
    float4 v = src[i];
    t[c+i*4+0][r] = f2bf(v.x);
    t[c+i*4+1][r] = f2bf(v.y);
    t[c+i*4+2][r] = f2bf(v.z);
    t[c+i*4+3][r] = f2bf(v.w);
  }
  __syncthreads();
  uint4* dst = (uint4*)(wt + ib + (size_t)(h0 + r) * DM + d0 + c);
  dst[0] = *(const uint4*)&t[r][c];
  dst[1] = *(const uint4*)&t[r][c+8];
}

// ---------------- router: one wave per token, COMBINED top-2 list ----------------
__global__ __launch_bounds__(64) void router_kernel(
    const float* __restrict__ x,
    const float* __restrict__ rw,
    int* __restrict__ cnt,            // [NE]
    int* __restrict__ tok,            // [NE*NT]
    float* __restrict__ gate)         // [NE*NT]
{
  const int t = blockIdx.x;
  const int lane = threadIdx.x;
  const float4* xr = (const float4*)(x + (size_t)t * DM);
  float4 xv[8];
  #pragma unroll
  for (int i = 0; i < 8; i++) xv[i] = xr[i*64 + lane];

  float logits[NE];
  #pragma unroll
  for (int e = 0; e < NE; e++){
    const float4* wr = (const float4*)(rw + e * DM);
    float s = 0.f;
    #pragma unroll
    for (int i = 0; i < 8; i++){
      float4 wv = wr[i*64 + lane];
      s += xv[i].x*wv.x + xv[i].y*wv.y + xv[i].z*wv.z + xv[i].w*wv.w;
    }
    #pragma unroll
    for (int o = 32; o > 0; o >>= 1) s += __shfl_xor(s, o, 64);
    logits[e] = s;
  }
  if (lane == 0){
    int i1 = 0; float v1 = logits[0];
    #pragma unroll
    for (int e = 1; e < NE; e++) if (logits[e] > v1){ v1 = logits[e]; i1 = e; }
    int i2 = -1; float v2 = -3.4e38f;
    #pragma unroll
    for (int e = 0; e < NE; e++) if (e != i1 && logits[e] > v2){ v2 = logits[e]; i2 = e; }
    float ex = __expf(v2 - v1);        // <= 1, stable
    float g1 = 1.f / (1.f + ex);
    float g2 = ex / (1.f + ex);
    int p1 = atomicAdd(&cnt[i1], 1);
    tok[i1*NT + p1] = t;  gate[i1*NT + p1] = g1;
    int p2 = atomicAdd(&cnt[i2], 1);
    tok[i2*NT + p2] = t;  gate[i2*NT + p2] = g2;
  }
}

// ---------------- grouped GEMM, one launch, atomic accumulate ----------------
// out[t][h] += g * sum_d x[t][d] * W[e][d][h]; rows gathered via combined list.
// BF16 path: xb bf16 [t][d], wt bf16 [e][h][d] (pre-transposed), both staged
// via global_load_lds with XOR-swizzled source chunks (LDS stays linear).
template<bool BF16>
__global__ __launch_bounds__(256) void moe_gemm(
    const float* __restrict__ xf, const unsigned short* __restrict__ xb,
    const float* __restrict__ wf, const unsigned short* __restrict__ wt,
    const int* __restrict__ cnt,
    const int* __restrict__ tok,
    const float* __restrict__ gate,
    float* __restrict__ out)
{
  constexpr int BM = 128, BN = 128, BK = 64;
  const int e = blockIdx.z;
  const int count = cnt[e];
  const int m0 = blockIdx.y * BM;
  if (m0 >= count) return;
  const int n0 = blockIdx.x * BN;
  const int tid = threadIdx.x;
  const int wave = tid >> 6, lane = tid & 63;

  const int* tokE = tok + e*NT;
  const float* gateE = gate + e*NT;
  const int mB = (wave & 1) * 64, nB = (wave >> 1) * 64;
  const int lrow = lane & 15, lgrp = lane >> 4;

  floatx4 acc[4][4];
  #pragma unroll
  for (int i = 0; i < 4; i++)
    #pragma unroll
    for (int j = 0; j < 4; j++) acc[i][j] = (floatx4){0.f, 0.f, 0.f, 0.f};

  if constexpr (BF16){
    // LDS linear [row][64] bf16; slot s=(wave*4+i)*64+lane covers row=s>>3, chunk=s&7.
    // Source chunk pre-swizzled: LDS[row][kc] holds global chunk kc^(row&7).
    __shared__ __align__(16) unsigned short As[BM*BK];
    __shared__ __align__(16) unsigned short Bs[BN*BK];

    const int kcs = ((lane & 7) ^ (lane >> 3)) * 8;   // element offset in row
    const unsigned short* sA[4];
    const unsigned short* sB[4];
    #pragma unroll
    for (int i = 0; i < 4; i++){
      const int row = (wave*4 + i)*8 + (lane >> 3);
      int gr = m0 + row; if (gr > count - 1) gr = count - 1;   // clamp; gated at store
      sA[i] = xb + (size_t)tokE[gr]*DM + kcs;
      sB[i] = wt + ((size_t)e*DH + n0 + row)*DM + kcs;
    }

    for (int s = 0; s < DM/BK; s++){
      const int k0 = s * BK;
      if (s) __syncthreads();                 // protect LDS overwrite
      #pragma unroll
      for (int i = 0; i < 4; i++) gload_lds16(sA[i] + k0, &As[(wave*4 + i)*512]);
      #pragma unroll
      for (int i = 0; i < 4; i++) gload_lds16(sB[i] + k0, &Bs[(wave*4 + i)*512]);
      __syncthreads();                        // compiler drains vmcnt before barrier

      #pragma unroll
      for (int kk = 0; kk < 2; kk++){
        short8 af[4], bfr[4];
        #pragma unroll
        for (int i = 0; i < 4; i++){
          const int row = mB + i*16 + lrow;
          af[i]  = *(const short8*)&As[row*64 + (((kk*4 + lgrp) ^ (row & 7)) * 8)];
        }
        #pragma unroll
        for (int j = 0; j < 4; j++){
          const int row = nB + j*16 + lrow;
          bfr[j] = *(const short8*)&Bs[row*64 + (((kk*4 + lgrp) ^ (row & 7)) * 8)];
        }
        #pragma unroll
        for (int i = 0; i < 4; i++)
          #pragma unroll
          for (int j = 0; j < 4; j++)
            acc[i][j] = __builtin_amdgcn_mfma_f32_16x16x32_bf16(af[i], bfr[j], acc[i][j], 0, 0, 0);
      }
    }
  } else {
    // fallback: f32 sources, register-staged with convert + perm transpose (old path)
    constexpr int LDK = 72;
    __shared__ __align__(16) unsigned short As[BM][LDK];
    __shared__ __align__(16) unsigned short Bs[BN][LDK];

    const int srowA = tid >> 3;   // 0..31 (x4 iters of +32 rows)
    const int kcA   = tid & 7;
    const int hp = tid & 31;
    const int dp = tid >> 5;

    int tokr[4];
    #pragma unroll
    for (int it = 0; it < 4; it++){
      int gr = m0 + srowA + it*32;
      if (gr > count - 1) gr = count - 1;
      tokr[it] = tokE[gr];
    }
    const size_t ebase = (size_t)e * DM * DH;

    float4 raf[8];
    float4 rbf[8];
    unsigned rbw[16];

    #pragma unroll
    for (int it = 0; it < 4; it++){
      const float4* p = (const float4*)&xf[(size_t)tokr[it]*DM + kcA*8];
      raf[it*2] = p[0]; raf[it*2+1] = p[1];
    }
    #pragma unroll
    for (int r = 0; r < 8; r++)
      rbf[r] = *(const float4*)&wf[ebase + (size_t)(dp*8 + r)*DH + n0 + hp*4];

    constexpr int S = DM / BK;
    for (int s = 0; s < S; s++){
      __syncthreads();
      #pragma unroll
      for (int it = 0; it < 4; it++){
        uint4 u;
        u.x = pk(raf[it*2].x,   raf[it*2].y);
        u.y = pk(raf[it*2].z,   raf[it*2].w);
        u.z = pk(raf[it*2+1].x, raf[it*2+1].y);
        u.w = pk(raf[it*2+1].z, raf[it*2+1].w);
        *(uint4*)&As[srowA + it*32][kcA*8] = u;
      }
      #pragma unroll
      for (int r = 0; r < 8; r++){
        rbw[r*2]   = pk(rbf[r].x, rbf[r].y);
        rbw[r*2+1] = pk(rbf[r].z, rbf[r].w);
      }
      #pragma unroll
      for (int j = 0; j < 4; j++){
        const unsigned sel = (j & 1) ? 0x07060302u : 0x05040100u;
        const int half = j >> 1;
        uint4 wv;
        wv.x = __builtin_amdgcn_perm(rbw[1*2+half], rbw[0*2+half], sel);
        wv.y = __builtin_amdgcn_perm(rbw[3*2+half], rbw[2*2+half], sel);
        wv.z = __builtin_amdgcn_perm(rbw[5*2+half], rbw[4*2+half], sel);
        wv.w = __builtin_amdgcn_perm(rbw[7*2+half], rbw[6*2+half], sel);
        *(uint4*)&Bs[hp*4 + j][dp*8] = wv;
      }
      __syncthreads();
      if (s + 1 < S){
        const int k0 = (s + 1) * BK;
        #pragma unroll
        for (int it = 0; it < 4; it++){
          const float4* p = (const float4*)&xf[(size_t)tokr[it]*DM + k0 + kcA*8];
          raf[it*2] = p[0]; raf[it*2+1] = p[1];
        }
        #pragma unroll
        for (int r = 0; r < 8; r++)
          rbf[r] = *(const float4*)&wf[ebase + (size_t)(k0 + dp*8 + r)*DH + n0 + hp*4];
      }
      #pragma unroll
      for (int kk = 0; kk < 2; kk++){
        const int kof = kk*32 + lgrp*8;
        short8 af[4], bfr[4];
        #pragma unroll
        for (int i = 0; i < 4; i++) af[i]  = *(const short8*)&As[mB + i*16 + lrow][kof];
        #pragma unroll
        for (int j = 0; j < 4; j++) bfr[j] = *(const short8*)&Bs[nB + j*16 + lrow][kof];
        #pragma unroll
        for (int i = 0; i < 4; i++)
          #pragma unroll
          for (int j = 0; j < 4; j++)
            acc[i][j] = __builtin_amdgcn_mfma_f32_16x16x32_bf16(af[i], bfr[j], acc[i][j], 0, 0, 0);
      }
    }
  }

  // ---- epilogue: atomic accumulate (each out element gets exactly 2 adds,
  //      commutative -> deterministic). C row = lgrp*4 + r, col = lrow per 16x16.
  #pragma unroll
  for (int i = 0; i < 4; i++){
    #pragma unroll
    for (int r = 0; r < 4; r++){
      const int rloc = mB + i*16 + lgrp*4 + r;
      const int gr = m0 + rloc;
      if (gr < count){
        const int t = tokE[gr];
        const float g = gateE[gr];
        float* orow = out + (size_t)t*DH + n0 + nB;
        #pragma unroll
        for (int j = 0; j < 4; j++)
          atomicAdd(&orow[j*16 + lrow], acc[i][j][r] * g);
      }
    }
  }
}

extern "C" void kernel_launch(void* const* d_in, const int* in_sizes, int n_in,
                              void* d_out, int out_size, void* d_ws, size_t ws_size,
                              hipStream_t stream) {
  const float* x  = (const float*)d_in[0];
  const float* rw = (const float*)d_in[1];
  const float* w  = (const float*)d_in[2];
  float* out = (float*)d_out;

  char* ws = (char*)d_ws;
  int* cnt = (int*)ws;
  int* tok = (int*)(ws + 256);
  float* gate = (float*)(ws + 256 + (size_t)NE*NT*4);
  const size_t base = 256 + (size_t)2*NE*NT*4;            // 1,048,832 B, 16B-aligned
  unsigned short* xb = (unsigned short*)(ws + base);
  unsigned short* wt = (unsigned short*)(ws + base + (size_t)NT*DM*2);
  const bool fast = ws_size >= base + (size_t)NT*DM*2 + (size_t)NE*DM*DH*2;

  hipMemsetAsync(cnt, 0, NE*sizeof(int), stream);
  hipMemsetAsync(out, 0, (size_t)NT*DH*sizeof(float), stream);
  router_kernel<<<NT, 64, 0, stream>>>(x, rw, cnt, tok, gate);

  dim3 gg(DH/128, NT/128, NE);
  if (fast){
    cvt_kernel<<<(NT*DM/4 + 255)/256, 256, 0, stream>>>((const float4*)x, (uint2*)xb, NT*DM/4);
    cvt_wt_kernel<<<dim3(DH/64, DM/64, NE), 256, 0, stream>>>(w, wt);
    moe_gemm<true ><<<gg, 256, 0, stream>>>(x, xb, w, wt, cnt, tok, gate, out);
  } else {
    moe_gemm<false><<<gg, 256, 0, stream>>>(x, xb, w, wt, cnt, tok, gate, out);
  }
}

// Round 2
// 881.513 us; speedup vs baseline: 1.3503x; 1.0159x over previous
//
#include <hip/hip_runtime.h>

#define NT 8192
#define DM 2048
#define DH 2048
#define NE 16

typedef __attribute__((ext_vector_type(8))) short short8;
typedef __attribute__((ext_vector_type(4))) float floatx4;

__device__ __forceinline__ unsigned short f2bf(float f){
  union { float f; unsigned u; } c; c.f = f;
  unsigned r = 0x7FFFu + ((c.u >> 16) & 1u);
  return (unsigned short)((c.u + r) >> 16);
}
// pack two floats as adjacent bf16 (lo in low 16 bits)
__device__ __forceinline__ unsigned pk(float lo, float hi){
  return ((unsigned)f2bf(hi) << 16) | (unsigned)f2bf(lo);
}

// async global -> LDS, 16B per lane; LDS dest is wave-uniform base + lane*16
__device__ __forceinline__ void gload_lds16(const void* g, void* l){
  __builtin_amdgcn_global_load_lds(
      (__attribute__((address_space(1))) void*)(unsigned long long)g,
      (__attribute__((address_space(3))) void*)l, 16, 0, 0);
}

// ---------------- f32 -> bf16 bulk convert (x) ----------------
__global__ __launch_bounds__(256) void cvt_kernel(
    const float4* __restrict__ src, uint2* __restrict__ dst, int n4)
{
  int i = blockIdx.x * 256 + threadIdx.x;
  if (i < n4){
    float4 v = src[i];
    dst[i] = make_uint2(pk(v.x, v.y), pk(v.z, v.w));
  }
}

// ------- f32 [e][d][h] -> bf16 [e][h][d] transpose+convert, 64x64 tiles -------
__global__ __launch_bounds__(256) void cvt_wt_kernel(
    const float* __restrict__ w, unsigned short* __restrict__ wt)
{
  __shared__ unsigned short t[64][72];   // pad 72 -> 16B-aligned row chunks
  const int e = blockIdx.z;
  const int h0 = blockIdx.x * 64, d0 = blockIdx.y * 64;
  const size_t ib = (size_t)e * DM * DH;
  const int r = threadIdx.x >> 2;          // 0..63
  const int c = (threadIdx.x & 3) * 16;    // 0,16,32,48
  const float4* src = (const float4*)(w + ib + (size_t)(d0 + r) * DH + h0 + c);
  #pragma unroll
  for (int i = 0; i < 4; i++){
    float4 v = src[i];
    t[c+i*4+0][r] = f2bf(v.x);
    t[c+i*4+1][r] = f2bf(v.y);
    t[c+i*4+2][r] = f2bf(v.z);
    t[c+i*4+3][r] = f2bf(v.w);
  }
  __syncthreads();
  uint4* dst = (uint4*)(wt + ib + (size_t)(h0 + r) * DM + d0 + c);
  dst[0] = *(const uint4*)&t[r][c];
  dst[1] = *(const uint4*)&t[r][c+8];
}

// ---------------- router: 32 threads/token, 8 tokens/block ----------------
// Each thread accumulates all 16 expert partials over interleaved k-slices
// (k = i*128 + s*4): coalesced 512B x/w reads, 8KB L1-hot weight window,
// 16 independent FMA chains. 5-step shfl_xor reduce, leader top-2 + atomics.
__global__ __launch_bounds__(256) void router_kernel(
    const float* __restrict__ x,
    const float* __restrict__ rw,
    int* __restrict__ cnt,            // [NE]
    int* __restrict__ tok,            // [NE*NT]
    float* __restrict__ gate)         // [NE*NT]
{
  const int tid = threadIdx.x;
  const int s = tid & 31;                      // k-slice within token
  const int t = blockIdx.x * 8 + (tid >> 5);   // token
  const float* xrow = x + (size_t)t * DM;

  float lg[NE];
  #pragma unroll
  for (int e = 0; e < NE; e++) lg[e] = 0.f;

  #pragma unroll
  for (int i = 0; i < DM/128; i++){
    const int k = i*128 + s*4;
    float4 xv = *(const float4*)&xrow[k];
    #pragma unroll
    for (int e = 0; e < NE; e++){
      float4 wv = *(const float4*)&rw[e*DM + k];
      lg[e] += xv.x*wv.x + xv.y*wv.y + xv.z*wv.z + xv.w*wv.w;
    }
  }

  // reduce over the 32 lanes of this token (xor 16,8,4,2,1 stays in-half)
  #pragma unroll
  for (int e = 0; e < NE; e++){
    #pragma unroll
    for (int o = 16; o > 0; o >>= 1) lg[e] += __shfl_xor(lg[e], o, 64);
  }

  if (s == 0){
    int i1 = 0; float v1 = lg[0];
    #pragma unroll
    for (int e = 1; e < NE; e++) if (lg[e] > v1){ v1 = lg[e]; i1 = e; }
    int i2 = -1; float v2 = -3.4e38f;
    #pragma unroll
    for (int e = 0; e < NE; e++) if (e != i1 && lg[e] > v2){ v2 = lg[e]; i2 = e; }
    float ex = __expf(v2 - v1);        // <= 1, stable
    float g1 = 1.f / (1.f + ex);
    float g2 = ex / (1.f + ex);
    int p1 = atomicAdd(&cnt[i1], 1);
    tok[i1*NT + p1] = t;  gate[i1*NT + p1] = g1;
    int p2 = atomicAdd(&cnt[i2], 1);
    tok[i2*NT + p2] = t;  gate[i2*NT + p2] = g2;
  }
}

// ---------------- grouped GEMM, one launch, atomic accumulate ----------------
// out[t][h] += g * sum_d x[t][d] * W[e][d][h]; rows gathered via combined list.
// BF16 path: xb bf16 [t][d], wt bf16 [e][h][d] (pre-transposed), both staged
// via global_load_lds with XOR-swizzled source chunks (LDS stays linear).
template<bool BF16>
__global__ __launch_bounds__(256) void moe_gemm(
    const float* __restrict__ xf, const unsigned short* __restrict__ xb,
    const float* __restrict__ wf, const unsigned short* __restrict__ wt,
    const int* __restrict__ cnt,
    const int* __restrict__ tok,
    const float* __restrict__ gate,
    float* __restrict__ out)
{
  constexpr int BM = 128, BN = 128, BK = 64;
  const int e = blockIdx.z;
  const int count = cnt[e];
  const int m0 = blockIdx.y * BM;
  if (m0 >= count) return;
  const int n0 = blockIdx.x * BN;
  const int tid = threadIdx.x;
  const int wave = tid >> 6, lane = tid & 63;

  const int* tokE = tok + e*NT;
  const float* gateE = gate + e*NT;
  const int mB = (wave & 1) * 64, nB = (wave >> 1) * 64;
  const int lrow = lane & 15, lgrp = lane >> 4;

  floatx4 acc[4][4];
  #pragma unroll
  for (int i = 0; i < 4; i++)
    #pragma unroll
    for (int j = 0; j < 4; j++) acc[i][j] = (floatx4){0.f, 0.f, 0.f, 0.f};

  if constexpr (BF16){
    // LDS linear [row][64] bf16; slot s=(wave*4+i)*64+lane covers row=s>>3, chunk=s&7.
    // Source chunk pre-swizzled: LDS[row][kc] holds global chunk kc^(row&7).
    __shared__ __align__(16) unsigned short As[BM*BK];
    __shared__ __align__(16) unsigned short Bs[BN*BK];

    const int kcs = ((lane & 7) ^ (lane >> 3)) * 8;   // element offset in row
    const unsigned short* sA[4];
    const unsigned short* sB[4];
    #pragma unroll
    for (int i = 0; i < 4; i++){
      const int row = (wave*4 + i)*8 + (lane >> 3);
      int gr = m0 + row; if (gr > count - 1) gr = count - 1;   // clamp; gated at store
      sA[i] = xb + (size_t)tokE[gr]*DM + kcs;
      sB[i] = wt + ((size_t)e*DH + n0 + row)*DM + kcs;
    }

    for (int s = 0; s < DM/BK; s++){
      const int k0 = s * BK;
      if (s) __syncthreads();                 // protect LDS overwrite
      #pragma unroll
      for (int i = 0; i < 4; i++) gload_lds16(sA[i] + k0, &As[(wave*4 + i)*512]);
      #pragma unroll
      for (int i = 0; i < 4; i++) gload_lds16(sB[i] + k0, &Bs[(wave*4 + i)*512]);
      __syncthreads();                        // compiler drains vmcnt before barrier

      #pragma unroll
      for (int kk = 0; kk < 2; kk++){
        short8 af[4], bfr[4];
        #pragma unroll
        for (int i = 0; i < 4; i++){
          const int row = mB + i*16 + lrow;
          af[i]  = *(const short8*)&As[row*64 + (((kk*4 + lgrp) ^ (row & 7)) * 8)];
        }
        #pragma unroll
        for (int j = 0; j < 4; j++){
          const int row = nB + j*16 + lrow;
          bfr[j] = *(const short8*)&Bs[row*64 + (((kk*4 + lgrp) ^ (row & 7)) * 8)];
        }
        #pragma unroll
        for (int i = 0; i < 4; i++)
          #pragma unroll
          for (int j = 0; j < 4; j++)
            acc[i][j] = __builtin_amdgcn_mfma_f32_16x16x32_bf16(af[i], bfr[j], acc[i][j], 0, 0, 0);
      }
    }
  } else {
    // fallback: f32 sources, register-staged with convert + perm transpose (old path)
    constexpr int LDK = 72;
    __shared__ __align__(16) unsigned short As[BM][LDK];
    __shared__ __align__(16) unsigned short Bs[BN][LDK];

    const int srowA = tid >> 3;   // 0..31 (x4 iters of +32 rows)
    const int kcA   = tid & 7;
    const int hp = tid & 31;
    const int dp = tid >> 5;

    int tokr[4];
    #pragma unroll
    for (int it = 0; it < 4; it++){
      int gr = m0 + srowA + it*32;
      if (gr > count - 1) gr = count - 1;
      tokr[it] = tokE[gr];
    }
    const size_t ebase = (size_t)e * DM * DH;

    float4 raf[8];
    float4 rbf[8];
    unsigned rbw[16];

    #pragma unroll
    for (int it = 0; it < 4; it++){
      const float4* p = (const float4*)&xf[(size_t)tokr[it]*DM + kcA*8];
      raf[it*2] = p[0]; raf[it*2+1] = p[1];
    }
    #pragma unroll
    for (int r = 0; r < 8; r++)
      rbf[r] = *(const float4*)&wf[ebase + (size_t)(dp*8 + r)*DH + n0 + hp*4];

    constexpr int S = DM / BK;
    for (int s = 0; s < S; s++){
      __syncthreads();
      #pragma unroll
      for (int it = 0; it < 4; it++){
        uint4 u;
        u.x = pk(raf[it*2].x,   raf[it*2].y);
        u.y = pk(raf[it*2].z,   raf[it*2].w);
        u.z = pk(raf[it*2+1].x, raf[it*2+1].y);
        u.w = pk(raf[it*2+1].z, raf[it*2+1].w);
        *(uint4*)&As[srowA + it*32][kcA*8] = u;
      }
      #pragma unroll
      for (int r = 0; r < 8; r++){
        rbw[r*2]   = pk(rbf[r].x, rbf[r].y);
        rbw[r*2+1] = pk(rbf[r].z, rbf[r].w);
      }
      #pragma unroll
      for (int j = 0; j < 4; j++){
        const unsigned sel = (j & 1) ? 0x07060302u : 0x05040100u;
        const int half = j >> 1;
        uint4 wv;
        wv.x = __builtin_amdgcn_perm(rbw[1*2+half], rbw[0*2+half], sel);
        wv.y = __builtin_amdgcn_perm(rbw[3*2+half], rbw[2*2+half], sel);
        wv.z = __builtin_amdgcn_perm(rbw[5*2+half], rbw[4*2+half], sel);
        wv.w = __builtin_amdgcn_perm(rbw[7*2+half], rbw[6*2+half], sel);
        *(uint4*)&Bs[hp*4 + j][dp*8] = wv;
      }
      __syncthreads();
      if (s + 1 < S){
        const int k0 = (s + 1) * BK;
        #pragma unroll
        for (int it = 0; it < 4; it++){
          const float4* p = (const float4*)&xf[(size_t)tokr[it]*DM + k0 + kcA*8];
          raf[it*2] = p[0]; raf[it*2+1] = p[1];
        }
        #pragma unroll
        for (int r = 0; r < 8; r++)
          rbf[r] = *(const float4*)&wf[ebase + (size_t)(k0 + dp*8 + r)*DH + n0 + hp*4];
      }
      #pragma unroll
      for (int kk = 0; kk < 2; kk++){
        const int kof = kk*32 + lgrp*8;
        short8 af[4], bfr[4];
        #pragma unroll
        for (int i = 0; i < 4; i++) af[i]  = *(const short8*)&As[mB + i*16 + lrow][kof];
        #pragma unroll
        for (int j = 0; j < 4; j++) bfr[j] = *(const short8*)&Bs[nB + j*16 + lrow][kof];
        #pragma unroll
        for (int i = 0; i < 4; i++)
          #pragma unroll
          for (int j = 0; j < 4; j++)
            acc[i][j] = __builtin_amdgcn_mfma_f32_16x16x32_bf16(af[i], bfr[j], acc[i][j], 0, 0, 0);
      }
    }
  }

  // ---- epilogue: atomic accumulate (each out element gets exactly 2 adds,
  //      commutative -> deterministic). C row = lgrp*4 + r, col = lrow per 16x16.
  #pragma unroll
  for (int i = 0; i < 4; i++){
    #pragma unroll
    for (int r = 0; r < 4; r++){
      const int rloc = mB + i*16 + lgrp*4 + r;
      const int gr = m0 + rloc;
      if (gr < count){
        const int t = tokE[gr];
        const float g = gateE[gr];
        float* orow = out + (size_t)t*DH + n0 + nB;
        #pragma unroll
        for (int j = 0; j < 4; j++)
          atomicAdd(&orow[j*16 + lrow], acc[i][j][r] * g);
      }
    }
  }
}

extern "C" void kernel_launch(void* const* d_in, const int* in_sizes, int n_in,
                              void* d_out, int out_size, void* d_ws, size_t ws_size,
                              hipStream_t stream) {
  const float* x  = (const float*)d_in[0];
  const float* rw = (const float*)d_in[1];
  const float* w  = (const float*)d_in[2];
  float* out = (float*)d_out;

  char* ws = (char*)d_ws;
  int* cnt = (int*)ws;
  int* tok = (int*)(ws + 256);
  float* gate = (float*)(ws + 256 + (size_t)NE*NT*4);
  const size_t base = 256 + (size_t)2*NE*NT*4;            // 1,048,832 B, 16B-aligned
  unsigned short* xb = (unsigned short*)(ws + base);
  unsigned short* wt = (unsigned short*)(ws + base + (size_t)NT*DM*2);
  const bool fast = ws_size >= base + (size_t)NT*DM*2 + (size_t)NE*DM*DH*2;

  hipMemsetAsync(cnt, 0, NE*sizeof(int), stream);
  hipMemsetAsync(out, 0, (size_t)NT*DH*sizeof(float), stream);
  router_kernel<<<NT/8, 256, 0, stream>>>(x, rw, cnt, tok, gate);

  dim3 gg(DH/128, NT/128, NE);
  if (fast){
    cvt_kernel<<<(NT*DM/4 + 255)/256, 256, 0, stream>>>((const float4*)x, (uint2*)xb, NT*DM/4);
    cvt_wt_kernel<<<dim3(DH/64, DM/64, NE), 256, 0, stream>>>(w, wt);
    moe_gemm<true ><<<gg, 256, 0, stream>>>(x, xb, w, wt, cnt, tok, gate, out);
  } else {
    moe_gemm<false><<<gg, 256, 0, stream>>>(x, xb, w, wt, cnt, tok, gate, out);
  }
}

// Round 3
// 815.601 us; speedup vs baseline: 1.4595x; 1.0808x over previous
//
#include <hip/hip_runtime.h>

#define NT 8192
#define DM 2048
#define DH 2048
#define NE 16
#define CSTRIDE 16   // ints per counter slot: 64B = one cacheline per expert

typedef __attribute__((ext_vector_type(8))) short short8;
typedef __attribute__((ext_vector_type(4))) float floatx4;

__device__ __forceinline__ unsigned short f2bf(float f){
  union { float f; unsigned u; } c; c.f = f;
  unsigned r = 0x7FFFu + ((c.u >> 16) & 1u);
  return (unsigned short)((c.u + r) >> 16);
}
// pack two floats as adjacent bf16 (lo in low 16 bits)
__device__ __forceinline__ unsigned pk(float lo, float hi){
  return ((unsigned)f2bf(hi) << 16) | (unsigned)f2bf(lo);
}

// async global -> LDS, 16B per lane; LDS dest is wave-uniform base + lane*16
__device__ __forceinline__ void gload_lds16(const void* g, void* l){
  __builtin_amdgcn_global_load_lds(
      (__attribute__((address_space(1))) void*)(unsigned long long)g,
      (__attribute__((address_space(3))) void*)l, 16, 0, 0);
}

// ---------------- f32 -> bf16 bulk convert (x) ----------------
__global__ __launch_bounds__(256) void cvt_kernel(
    const float4* __restrict__ src, uint2* __restrict__ dst, int n4)
{
  int i = blockIdx.x * 256 + threadIdx.x;
  if (i < n4){
    float4 v = src[i];
    dst[i] = make_uint2(pk(v.x, v.y), pk(v.z, v.w));
  }
}

// ------- f32 [e][d][h] -> bf16 [e][h][d] transpose+convert, 64x64 tiles -------
__global__ __launch_bounds__(256) void cvt_wt_kernel(
    const float* __restrict__ w, unsigned short* __restrict__ wt)
{
  __shared__ unsigned short t[64][72];   // pad 72 -> 16B-aligned row chunks
  const int e = blockIdx.z;
  const int h0 = blockIdx.x * 64, d0 = blockIdx.y * 64;
  const size_t ib = (size_t)e * DM * DH;
  const int r = threadIdx.x >> 2;          // 0..63
  const int c = (threadIdx.x & 3) * 16;    // 0,16,32,48
  const float4* src = (const float4*)(w + ib + (size_t)(d0 + r) * DH + h0 + c);
  #pragma unroll
  for (int i = 0; i < 4; i++){
    float4 v = src[i];
    t[c+i*4+0][r] = f2bf(v.x);
    t[c+i*4+1][r] = f2bf(v.y);
    t[c+i*4+2][r] = f2bf(v.z);
    t[c+i*4+3][r] = f2bf(v.w);
  }
  __syncthreads();
  uint4* dst = (uint4*)(wt + ib + (size_t)(h0 + r) * DM + d0 + c);
  dst[0] = *(const uint4*)&t[r][c];
  dst[1] = *(const uint4*)&t[r][c+8];
}

// ---------------- router: 32 threads/token, 8 tokens/block ----------------
// Counters padded to one cacheline per expert: the former single-line cnt[16]
// serialized all 16K atomics at one L2 home (~37cy each = ~250us).
__global__ __launch_bounds__(256) void router_kernel(
    const float* __restrict__ x,
    const float* __restrict__ rw,
    int* __restrict__ cnt,            // [NE*CSTRIDE], slot e at cnt[e*CSTRIDE]
    int* __restrict__ tok,            // [NE*NT]
    float* __restrict__ gate)         // [NE*NT]
{
  const int tid = threadIdx.x;
  const int s = tid & 31;                      // k-slice within token
  const int t = blockIdx.x * 8 + (tid >> 5);   // token
  const float* xrow = x + (size_t)t * DM;

  float lg[NE];
  #pragma unroll
  for (int e = 0; e < NE; e++) lg[e] = 0.f;

  #pragma unroll
  for (int i = 0; i < DM/128; i++){
    const int k = i*128 + s*4;
    float4 xv = *(const float4*)&xrow[k];
    #pragma unroll
    for (int e = 0; e < NE; e++){
      float4 wv = *(const float4*)&rw[e*DM + k];
      lg[e] += xv.x*wv.x + xv.y*wv.y + xv.z*wv.z + xv.w*wv.w;
    }
  }

  // reduce over the 32 lanes of this token (xor 16,8,4,2,1 stays in-half)
  #pragma unroll
  for (int e = 0; e < NE; e++){
    #pragma unroll
    for (int o = 16; o > 0; o >>= 1) lg[e] += __shfl_xor(lg[e], o, 64);
  }

  if (s == 0){
    int i1 = 0; float v1 = lg[0];
    #pragma unroll
    for (int e = 1; e < NE; e++) if (lg[e] > v1){ v1 = lg[e]; i1 = e; }
    int i2 = -1; float v2 = -3.4e38f;
    #pragma unroll
    for (int e = 0; e < NE; e++) if (e != i1 && lg[e] > v2){ v2 = lg[e]; i2 = e; }
    float ex = __expf(v2 - v1);        // <= 1, stable
    float g1 = 1.f / (1.f + ex);
    float g2 = ex / (1.f + ex);
    int p1 = atomicAdd(&cnt[i1*CSTRIDE], 1);
    tok[i1*NT + p1] = t;  gate[i1*NT + p1] = g1;
    int p2 = atomicAdd(&cnt[i2*CSTRIDE], 1);
    tok[i2*NT + p2] = t;  gate[i2*NT + p2] = g2;
  }
}

// ---------------- grouped GEMM, one launch, atomic accumulate ----------------
// out[t][h] += g * sum_d x[t][d] * W[e][d][h]; rows gathered via combined list.
// BF16 path: xb bf16 [t][d], wt bf16 [e][h][d] (pre-transposed), both staged
// via global_load_lds with XOR-swizzled source chunks (LDS stays linear).
template<bool BF16>
__global__ __launch_bounds__(256) void moe_gemm(
    const float* __restrict__ xf, const unsigned short* __restrict__ xb,
    const float* __restrict__ wf, const unsigned short* __restrict__ wt,
    const int* __restrict__ cnt,
    const int* __restrict__ tok,
    const float* __restrict__ gate,
    float* __restrict__ out)
{
  constexpr int BM = 128, BN = 128, BK = 64;
  const int e = blockIdx.z;
  const int count = cnt[e*CSTRIDE];
  const int m0 = blockIdx.y * BM;
  if (m0 >= count) return;
  const int n0 = blockIdx.x * BN;
  const int tid = threadIdx.x;
  const int wave = tid >> 6, lane = tid & 63;

  const int* tokE = tok + e*NT;
  const float* gateE = gate + e*NT;
  const int mB = (wave & 1) * 64, nB = (wave >> 1) * 64;
  const int lrow = lane & 15, lgrp = lane >> 4;

  floatx4 acc[4][4];
  #pragma unroll
  for (int i = 0; i < 4; i++)
    #pragma unroll
    for (int j = 0; j < 4; j++) acc[i][j] = (floatx4){0.f, 0.f, 0.f, 0.f};

  if constexpr (BF16){
    // LDS linear [row][64] bf16; slot s=(wave*4+i)*64+lane covers row=s>>3, chunk=s&7.
    // Source chunk pre-swizzled: LDS[row][kc] holds global chunk kc^(row&7).
    __shared__ __align__(16) unsigned short As[BM*BK];
    __shared__ __align__(16) unsigned short Bs[BN*BK];

    const int kcs = ((lane & 7) ^ (lane >> 3)) * 8;   // element offset in row
    const unsigned short* sA[4];
    const unsigned short* sB[4];
    #pragma unroll
    for (int i = 0; i < 4; i++){
      const int row = (wave*4 + i)*8 + (lane >> 3);
      int gr = m0 + row; if (gr > count - 1) gr = count - 1;   // clamp; gated at store
      sA[i] = xb + (size_t)tokE[gr]*DM + kcs;
      sB[i] = wt + ((size_t)e*DH + n0 + row)*DM + kcs;
    }

    for (int s = 0; s < DM/BK; s++){
      const int k0 = s * BK;
      if (s) __syncthreads();                 // protect LDS overwrite
      #pragma unroll
      for (int i = 0; i < 4; i++) gload_lds16(sA[i] + k0, &As[(wave*4 + i)*512]);
      #pragma unroll
      for (int i = 0; i < 4; i++) gload_lds16(sB[i] + k0, &Bs[(wave*4 + i)*512]);
      __syncthreads();                        // compiler drains vmcnt before barrier

      #pragma unroll
      for (int kk = 0; kk < 2; kk++){
        short8 af[4], bfr[4];
        #pragma unroll
        for (int i = 0; i < 4; i++){
          const int row = mB + i*16 + lrow;
          af[i]  = *(const short8*)&As[row*64 + (((kk*4 + lgrp) ^ (row & 7)) * 8)];
        }
        #pragma unroll
        for (int j = 0; j < 4; j++){
          const int row = nB + j*16 + lrow;
          bfr[j] = *(const short8*)&Bs[row*64 + (((kk*4 + lgrp) ^ (row & 7)) * 8)];
        }
        #pragma unroll
        for (int i = 0; i < 4; i++)
          #pragma unroll
          for (int j = 0; j < 4; j++)
            acc[i][j] = __builtin_amdgcn_mfma_f32_16x16x32_bf16(af[i], bfr[j], acc[i][j], 0, 0, 0);
      }
    }
  } else {
    // fallback: f32 sources, register-staged with convert + perm transpose (old path)
    constexpr int LDK = 72;
    __shared__ __align__(16) unsigned short As[BM][LDK];
    __shared__ __align__(16) unsigned short Bs[BN][LDK];

    const int srowA = tid >> 3;   // 0..31 (x4 iters of +32 rows)
    const int kcA   = tid & 7;
    const int hp = tid & 31;
    const int dp = tid >> 5;

    int tokr[4];
    #pragma unroll
    for (int it = 0; it < 4; it++){
      int gr = m0 + srowA + it*32;
      if (gr > count - 1) gr = count - 1;
      tokr[it] = tokE[gr];
    }
    const size_t ebase = (size_t)e * DM * DH;

    float4 raf[8];
    float4 rbf[8];
    unsigned rbw[16];

    #pragma unroll
    for (int it = 0; it < 4; it++){
      const float4* p = (const float4*)&xf[(size_t)tokr[it]*DM + kcA*8];
      raf[it*2] = p[0]; raf[it*2+1] = p[1];
    }
    #pragma unroll
    for (int r = 0; r < 8; r++)
      rbf[r] = *(const float4*)&wf[ebase + (size_t)(dp*8 + r)*DH + n0 + hp*4];

    constexpr int S = DM / BK;
    for (int s = 0; s < S; s++){
      __syncthreads();
      #pragma unroll
      for (int it = 0; it < 4; it++){
        uint4 u;
        u.x = pk(raf[it*2].x,   raf[it*2].y);
        u.y = pk(raf[it*2].z,   raf[it*2].w);
        u.z = pk(raf[it*2+1].x, raf[it*2+1].y);
        u.w = pk(raf[it*2+1].z, raf[it*2+1].w);
        *(uint4*)&As[srowA + it*32][kcA*8] = u;
      }
      #pragma unroll
      for (int r = 0; r < 8; r++){
        rbw[r*2]   = pk(rbf[r].x, rbf[r].y);
        rbw[r*2+1] = pk(rbf[r].z, rbf[r].w);
      }
      #pragma unroll
      for (int j = 0; j < 4; j++){
        const unsigned sel = (j & 1) ? 0x07060302u : 0x05040100u;
        const int half = j >> 1;
        uint4 wv;
        wv.x = __builtin_amdgcn_perm(rbw[1*2+half], rbw[0*2+half], sel);
        wv.y = __builtin_amdgcn_perm(rbw[3*2+half], rbw[2*2+half], sel);
        wv.z = __builtin_amdgcn_perm(rbw[5*2+half], rbw[4*2+half], sel);
        wv.w = __builtin_amdgcn_perm(rbw[7*2+half], rbw[6*2+half], sel);
        *(uint4*)&Bs[hp*4 + j][dp*8] = wv;
      }
      __syncthreads();
      if (s + 1 < S){
        const int k0 = (s + 1) * BK;
        #pragma unroll
        for (int it = 0; it < 4; it++){
          const float4* p = (const float4*)&xf[(size_t)tokr[it]*DM + k0 + kcA*8];
          raf[it*2] = p[0]; raf[it*2+1] = p[1];
        }
        #pragma unroll
        for (int r = 0; r < 8; r++)
          rbf[r] = *(const float4*)&wf[ebase + (size_t)(k0 + dp*8 + r)*DH + n0 + hp*4];
      }
      #pragma unroll
      for (int kk = 0; kk < 2; kk++){
        const int kof = kk*32 + lgrp*8;
        short8 af[4], bfr[4];
        #pragma unroll
        for (int i = 0; i < 4; i++) af[i]  = *(const short8*)&As[mB + i*16 + lrow][kof];
        #pragma unroll
        for (int j = 0; j < 4; j++) bfr[j] = *(const short8*)&Bs[nB + j*16 + lrow][kof];
        #pragma unroll
        for (int i = 0; i < 4; i++)
          #pragma unroll
          for (int j = 0; j < 4; j++)
            acc[i][j] = __builtin_amdgcn_mfma_f32_16x16x32_bf16(af[i], bfr[j], acc[i][j], 0, 0, 0);
      }
    }
  }

  // ---- epilogue: atomic accumulate (each out element gets exactly 2 adds,
  //      commutative -> deterministic). C row = lgrp*4 + r, col = lrow per 16x16.
  #pragma unroll
  for (int i = 0; i < 4; i++){
    #pragma unroll
    for (int r = 0; r < 4; r++){
      const int rloc = mB + i*16 + lgrp*4 + r;
      const int gr = m0 + rloc;
      if (gr < count){
        const int t = tokE[gr];
        const float g = gateE[gr];
        float* orow = out + (size_t)t*DH + n0 + nB;
        #pragma unroll
        for (int j = 0; j < 4; j++)
          atomicAdd(&orow[j*16 + lrow], acc[i][j][r] * g);
      }
    }
  }
}

extern "C" void kernel_launch(void* const* d_in, const int* in_sizes, int n_in,
                              void* d_out, int out_size, void* d_ws, size_t ws_size,
                              hipStream_t stream) {
  const float* x  = (const float*)d_in[0];
  const float* rw = (const float*)d_in[1];
  const float* w  = (const float*)d_in[2];
  float* out = (float*)d_out;

  char* ws = (char*)d_ws;
  int* cnt = (int*)ws;                                     // NE*CSTRIDE ints = 1KB
  int* tok = (int*)(ws + 1024);
  float* gate = (float*)(ws + 1024 + (size_t)NE*NT*4);
  const size_t base = 1024 + (size_t)2*NE*NT*4;            // 16B-aligned
  unsigned short* xb = (unsigned short*)(ws + base);
  unsigned short* wt = (unsigned short*)(ws + base + (size_t)NT*DM*2);
  const bool fast = ws_size >= base + (size_t)NT*DM*2 + (size_t)NE*DM*DH*2;

  hipMemsetAsync(cnt, 0, NE*CSTRIDE*sizeof(int), stream);
  hipMemsetAsync(out, 0, (size_t)NT*DH*sizeof(float), stream);
  router_kernel<<<NT/8, 256, 0, stream>>>(x, rw, cnt, tok, gate);

  dim3 gg(DH/128, NT/128, NE);
  if (fast){
    cvt_kernel<<<(NT*DM/4 + 255)/256, 256, 0, stream>>>((const float4*)x, (uint2*)xb, NT*DM/4);
    cvt_wt_kernel<<<dim3(DH/64, DM/64, NE), 256, 0, stream>>>(w, wt);
    moe_gemm<true ><<<gg, 256, 0, stream>>>(x, xb, w, wt, cnt, tok, gate, out);
  } else {
    moe_gemm<false><<<gg, 256, 0, stream>>>(x, xb, w, wt, cnt, tok, gate, out);
  }
}

// Round 4
// 810.574 us; speedup vs baseline: 1.4685x; 1.0062x over previous
//
#include <hip/hip_runtime.h>

#define NT 8192
#define DM 2048
#define DH 2048
#define NE 16
#define CSTRIDE 16   // ints per counter slot: 64B = one cacheline per counter

typedef __attribute__((ext_vector_type(8))) short short8;
typedef __attribute__((ext_vector_type(4))) float floatx4;

__device__ __forceinline__ unsigned short f2bf(float f){
  union { float f; unsigned u; } c; c.f = f;
  unsigned r = 0x7FFFu + ((c.u >> 16) & 1u);
  return (unsigned short)((c.u + r) >> 16);
}
// pack two floats as adjacent bf16 (lo in low 16 bits)
__device__ __forceinline__ unsigned pk(float lo, float hi){
  return ((unsigned)f2bf(hi) << 16) | (unsigned)f2bf(lo);
}

// async global -> LDS, 16B per lane; LDS dest is wave-uniform base + lane*16
__device__ __forceinline__ void gload_lds16(const void* g, void* l){
  __builtin_amdgcn_global_load_lds(
      (__attribute__((address_space(1))) void*)(unsigned long long)g,
      (__attribute__((address_space(3))) void*)l, 16, 0, 0);
}

// ------- f32 [e][d][h] -> bf16 [e][h][d] transpose+convert, 64h x 128d tiles -------
// All-vector version: b128 LDS writes/reads with XOR-swizzled 8-elem chunks.
__global__ __launch_bounds__(256) void cvt_wt_kernel(
    const float* __restrict__ w, unsigned short* __restrict__ wt)
{
  __shared__ __align__(16) unsigned short t[64*128];   // [h][d], swizzled chunks
  const int e = blockIdx.z;
  const int h0 = blockIdx.x * 64, d0 = blockIdx.y * 128;
  const size_t ib = (size_t)e * DM * DH;
  const int hq = threadIdx.x & 15;       // h-quad: h = hq*4 + 0..3
  const int dg = threadIdx.x >> 4;       // d-group: d = dg*8 + 0..7

  float4 v[8];
  #pragma unroll
  for (int r = 0; r < 8; r++)
    v[r] = *(const float4*)&w[ib + (size_t)(d0 + dg*8 + r)*DH + h0 + hq*4];

  const float* f = (const float*)v;      // f[r*4 + hh]
  #pragma unroll
  for (int hh = 0; hh < 4; hh++){
    uint4 u;
    u.x = pk(f[0*4+hh], f[1*4+hh]);
    u.y = pk(f[2*4+hh], f[3*4+hh]);
    u.z = pk(f[4*4+hh], f[5*4+hh]);
    u.w = pk(f[6*4+hh], f[7*4+hh]);      // 8 d-consecutive bf16 for row h
    const int h = hq*4 + hh;
    *(uint4*)&t[h*128 + ((dg ^ (h & 7)) * 8)] = u;
  }
  __syncthreads();
  #pragma unroll
  for (int j = 0; j < 4; j++){
    const int idx = j*256 + threadIdx.x;
    const int h = idx >> 4, c = idx & 15;
    uint4 u = *(const uint4*)&t[h*128 + ((c ^ (h & 7)) * 8)];
    *(uint4*)&wt[ib + (size_t)(h0 + h)*DM + d0 + c*8] = u;
  }
}

// ---------------- router: 32 threads/token, 8 tokens/block ----------------
// Fused: also emits xb (bf16 x) while x is in registers. Dual slot lists:
// slot0 (top-1) at cnt[e*CSTRIDE], slot1 (top-2) at cnt[(NE+e)*CSTRIDE].
template<bool WX>
__global__ __launch_bounds__(256) void router_kernel(
    const float* __restrict__ x,
    const float* __restrict__ rw,
    unsigned short* __restrict__ xb,
    int* __restrict__ cnt,            // [2*NE*CSTRIDE]
    int* __restrict__ tok,            // [2*NE*NT]
    float* __restrict__ gate)         // [2*NE*NT]
{
  const int tid = threadIdx.x;
  const int s = tid & 31;                      // k-slice within token
  const int t = blockIdx.x * 8 + (tid >> 5);   // token
  const float* xrow = x + (size_t)t * DM;

  float lg[NE];
  #pragma unroll
  for (int e = 0; e < NE; e++) lg[e] = 0.f;

  #pragma unroll
  for (int i = 0; i < DM/128; i++){
    const int k = i*128 + s*4;
    float4 xv = *(const float4*)&xrow[k];
    if (WX)
      *(uint2*)&xb[(size_t)t*DM + k] = make_uint2(pk(xv.x, xv.y), pk(xv.z, xv.w));
    #pragma unroll
    for (int e = 0; e < NE; e++){
      float4 wv = *(const float4*)&rw[e*DM + k];
      lg[e] += xv.x*wv.x + xv.y*wv.y + xv.z*wv.z + xv.w*wv.w;
    }
  }

  // reduce over the 32 lanes of this token (xor 16,8,4,2,1 stays in-half)
  #pragma unroll
  for (int e = 0; e < NE; e++){
    #pragma unroll
    for (int o = 16; o > 0; o >>= 1) lg[e] += __shfl_xor(lg[e], o, 64);
  }

  if (s == 0){
    int i1 = 0; float v1 = lg[0];
    #pragma unroll
    for (int e = 1; e < NE; e++) if (lg[e] > v1){ v1 = lg[e]; i1 = e; }
    int i2 = -1; float v2 = -3.4e38f;
    #pragma unroll
    for (int e = 0; e < NE; e++) if (e != i1 && lg[e] > v2){ v2 = lg[e]; i2 = e; }
    float ex = __expf(v2 - v1);        // <= 1, stable
    float g1 = 1.f / (1.f + ex);
    float g2 = ex / (1.f + ex);
    int p1 = atomicAdd(&cnt[i1*CSTRIDE], 1);
    tok[i1*NT + p1] = t;  gate[i1*NT + p1] = g1;
    int p2 = atomicAdd(&cnt[(NE + i2)*CSTRIDE], 1);
    tok[(NE + i2)*NT + p2] = t;  gate[(NE + i2)*NT + p2] = g2;
  }
}

// ---------------- grouped GEMM per (slot, expert) ----------------
// out[t][h] (+)= g * sum_d x[t][d] * W[e][d][h]; rows gathered via tok list.
// Slot0 launch: ADD=false, plain stores (covers every token once -> no memset).
// Slot1 launch: ADD=true, coalesced read+add+store. No atomics anywhere.
template<bool ADD, bool BF16>
__global__ __launch_bounds__(256) void moe_gemm(
    const float* __restrict__ xf, const unsigned short* __restrict__ xb,
    const float* __restrict__ wf, const unsigned short* __restrict__ wt,
    const int* __restrict__ cnt,
    const int* __restrict__ tok,
    const float* __restrict__ gate,
    float* __restrict__ out)
{
  constexpr int BM = 128, BN = 128, BK = 64;
  const int e = blockIdx.z;
  const int count = cnt[e*CSTRIDE];
  const int m0 = blockIdx.y * BM;
  if (m0 >= count) return;
  const int n0 = blockIdx.x * BN;
  const int tid = threadIdx.x;
  const int wave = tid >> 6, lane = tid & 63;

  const int* tokE = tok + e*NT;
  const float* gateE = gate + e*NT;
  const int mB = (wave & 1) * 64, nB = (wave >> 1) * 64;
  const int lrow = lane & 15, lgrp = lane >> 4;

  floatx4 acc[4][4];
  #pragma unroll
  for (int i = 0; i < 4; i++)
    #pragma unroll
    for (int j = 0; j < 4; j++) acc[i][j] = (floatx4){0.f, 0.f, 0.f, 0.f};

  if constexpr (BF16){
    // LDS linear [row][64] bf16; slot s=(wave*4+i)*64+lane covers row=s>>3, chunk=s&7.
    // Source chunk pre-swizzled: LDS[row][kc] holds global chunk kc^(row&7).
    __shared__ __align__(16) unsigned short As[BM*BK];
    __shared__ __align__(16) unsigned short Bs[BN*BK];

    const int kcs = ((lane & 7) ^ (lane >> 3)) * 8;   // element offset in row
    const unsigned short* sA[4];
    const unsigned short* sB[4];
    #pragma unroll
    for (int i = 0; i < 4; i++){
      const int row = (wave*4 + i)*8 + (lane >> 3);
      int gr = m0 + row; if (gr > count - 1) gr = count - 1;   // clamp; gated at store
      sA[i] = xb + (size_t)tokE[gr]*DM + kcs;
      sB[i] = wt + ((size_t)e*DH + n0 + row)*DM + kcs;
    }

    for (int s = 0; s < DM/BK; s++){
      const int k0 = s * BK;
      if (s) __syncthreads();                 // protect LDS overwrite
      #pragma unroll
      for (int i = 0; i < 4; i++) gload_lds16(sA[i] + k0, &As[(wave*4 + i)*512]);
      #pragma unroll
      for (int i = 0; i < 4; i++) gload_lds16(sB[i] + k0, &Bs[(wave*4 + i)*512]);
      __syncthreads();                        // compiler drains vmcnt before barrier

      #pragma unroll
      for (int kk = 0; kk < 2; kk++){
        short8 af[4], bfr[4];
        #pragma unroll
        for (int i = 0; i < 4; i++){
          const int row = mB + i*16 + lrow;
          af[i]  = *(const short8*)&As[row*64 + (((kk*4 + lgrp) ^ (row & 7)) * 8)];
        }
        #pragma unroll
        for (int j = 0; j < 4; j++){
          const int row = nB + j*16 + lrow;
          bfr[j] = *(const short8*)&Bs[row*64 + (((kk*4 + lgrp) ^ (row & 7)) * 8)];
        }
        #pragma unroll
        for (int i = 0; i < 4; i++)
          #pragma unroll
          for (int j = 0; j < 4; j++)
            acc[i][j] = __builtin_amdgcn_mfma_f32_16x16x32_bf16(af[i], bfr[j], acc[i][j], 0, 0, 0);
      }
    }
  } else {
    // fallback: f32 sources, register-staged with convert + perm transpose
    constexpr int LDK = 72;
    __shared__ __align__(16) unsigned short As[BM][LDK];
    __shared__ __align__(16) unsigned short Bs[BN][LDK];

    const int srowA = tid >> 3;   // 0..31 (x4 iters of +32 rows)
    const int kcA   = tid & 7;
    const int hp = tid & 31;
    const int dp = tid >> 5;

    int tokr[4];
    #pragma unroll
    for (int it = 0; it < 4; it++){
      int gr = m0 + srowA + it*32;
      if (gr > count - 1) gr = count - 1;
      tokr[it] = tokE[gr];
    }
    const size_t ebase = (size_t)e * DM * DH;

    float4 raf[8];
    float4 rbf[8];
    unsigned rbw[16];

    #pragma unroll
    for (int it = 0; it < 4; it++){
      const float4* p = (const float4*)&xf[(size_t)tokr[it]*DM + kcA*8];
      raf[it*2] = p[0]; raf[it*2+1] = p[1];
    }
    #pragma unroll
    for (int r = 0; r < 8; r++)
      rbf[r] = *(const float4*)&wf[ebase + (size_t)(dp*8 + r)*DH + n0 + hp*4];

    constexpr int S = DM / BK;
    for (int s = 0; s < S; s++){
      __syncthreads();
      #pragma unroll
      for (int it = 0; it < 4; it++){
        uint4 u;
        u.x = pk(raf[it*2].x,   raf[it*2].y);
        u.y = pk(raf[it*2].z,   raf[it*2].w);
        u.z = pk(raf[it*2+1].x, raf[it*2+1].y);
        u.w = pk(raf[it*2+1].z, raf[it*2+1].w);
        *(uint4*)&As[srowA + it*32][kcA*8] = u;
      }
      #pragma unroll
      for (int r = 0; r < 8; r++){
        rbw[r*2]   = pk(rbf[r].x, rbf[r].y);
        rbw[r*2+1] = pk(rbf[r].z, rbf[r].w);
      }
      #pragma unroll
      for (int j = 0; j < 4; j++){
        const unsigned sel = (j & 1) ? 0x07060302u : 0x05040100u;
        const int half = j >> 1;
        uint4 wv;
        wv.x = __builtin_amdgcn_perm(rbw[1*2+half], rbw[0*2+half], sel);
        wv.y = __builtin_amdgcn_perm(rbw[3*2+half], rbw[2*2+half], sel);
        wv.z = __builtin_amdgcn_perm(rbw[5*2+half], rbw[4*2+half], sel);
        wv.w = __builtin_amdgcn_perm(rbw[7*2+half], rbw[6*2+half], sel);
        *(uint4*)&Bs[hp*4 + j][dp*8] = wv;
      }
      __syncthreads();
      if (s + 1 < S){
        const int k0 = (s + 1) * BK;
        #pragma unroll
        for (int it = 0; it < 4; it++){
          const float4* p = (const float4*)&xf[(size_t)tokr[it]*DM + k0 + kcA*8];
          raf[it*2] = p[0]; raf[it*2+1] = p[1];
        }
        #pragma unroll
        for (int r = 0; r < 8; r++)
          rbf[r] = *(const float4*)&wf[ebase + (size_t)(k0 + dp*8 + r)*DH + n0 + hp*4];
      }
      #pragma unroll
      for (int kk = 0; kk < 2; kk++){
        const int kof = kk*32 + lgrp*8;
        short8 af[4], bfr[4];
        #pragma unroll
        for (int i = 0; i < 4; i++) af[i]  = *(const short8*)&As[mB + i*16 + lrow][kof];
        #pragma unroll
        for (int j = 0; j < 4; j++) bfr[j] = *(const short8*)&Bs[nB + j*16 + lrow][kof];
        #pragma unroll
        for (int i = 0; i < 4; i++)
          #pragma unroll
          for (int j = 0; j < 4; j++)
            acc[i][j] = __builtin_amdgcn_mfma_f32_16x16x32_bf16(af[i], bfr[j], acc[i][j], 0, 0, 0);
      }
    }
  }

  // ---- epilogue: plain (slot0) or read+add (slot1); no atomics ----
  #pragma unroll
  for (int i = 0; i < 4; i++){
    #pragma unroll
    for (int r = 0; r < 4; r++){
      const int rloc = mB + i*16 + lgrp*4 + r;
      const int gr = m0 + rloc;
      if (gr < count){
        const int t = tokE[gr];
        const float g = gateE[gr];
        float* orow = out + (size_t)t*DH + n0 + nB;
        #pragma unroll
        for (int j = 0; j < 4; j++){
          float v = acc[i][j][r] * g;
          const int col = j*16 + lrow;
          if (ADD) v += orow[col];
          orow[col] = v;
        }
      }
    }
  }
}

extern "C" void kernel_launch(void* const* d_in, const int* in_sizes, int n_in,
                              void* d_out, int out_size, void* d_ws, size_t ws_size,
                              hipStream_t stream) {
  const float* x  = (const float*)d_in[0];
  const float* rw = (const float*)d_in[1];
  const float* w  = (const float*)d_in[2];
  float* out = (float*)d_out;

  char* ws = (char*)d_ws;
  int* cnt = (int*)ws;                                     // 2*NE*CSTRIDE ints = 2KB
  int* tok = (int*)(ws + 2048);                            // 2*NE*NT ints = 1MB
  float* gate = (float*)(ws + 2048 + (size_t)2*NE*NT*4);   // 1MB
  const size_t base = 2048 + (size_t)4*NE*NT*4;            // 16B-aligned
  unsigned short* xb = (unsigned short*)(ws + base);
  unsigned short* wt = (unsigned short*)(ws + base + (size_t)NT*DM*2);
  const bool fast = ws_size >= base + (size_t)NT*DM*2 + (size_t)NE*DM*DH*2;

  hipMemsetAsync(cnt, 0, 2*NE*CSTRIDE*sizeof(int), stream);

  dim3 gg(DH/128, NT/128, NE);
  if (fast){
    router_kernel<true ><<<NT/8, 256, 0, stream>>>(x, rw, xb, cnt, tok, gate);
    cvt_wt_kernel<<<dim3(DH/64, DM/128, NE), 256, 0, stream>>>(w, wt);
    moe_gemm<false,true ><<<gg, 256, 0, stream>>>(x, xb, w, wt, cnt,             tok,       gate,       out);
    moe_gemm<true ,true ><<<gg, 256, 0, stream>>>(x, xb, w, wt, cnt+NE*CSTRIDE,  tok+NE*NT, gate+NE*NT, out);
  } else {
    router_kernel<false><<<NT/8, 256, 0, stream>>>(x, rw, xb, cnt, tok, gate);
    moe_gemm<false,false><<<gg, 256, 0, stream>>>(x, xb, w, wt, cnt,             tok,       gate,       out);
    moe_gemm<true ,false><<<gg, 256, 0, stream>>>(x, xb, w, wt, cnt+NE*CSTRIDE,  tok+NE*NT, gate+NE*NT, out);
  }
}